// Round 1
// 82.342 us; speedup vs baseline: 1.0109x; 1.0109x over previous
//
#include <hip/hip_runtime.h>

// CompressibleOgden: W = sum_k mu_k/alpha_k * (sum_i lamb_i^(alpha_k/2) - 3)
//                      + KAPPA/BETA^2 * (J^BETA - BETA*ln J - 1)
// lamb = eigvals of Cb = J^(-2/3) * F^T F,  J = sqrt(det(F^T F)) = |det F|
// KAPPA=100, BETA=2 compile-time constants per reference.
//
// R6 (this round): kernel portion was ~37.7us vs ~6.5us BW / ~4us issue floor
//   -> latency-bound on one serial transcendental chain per lane. Changes:
//   * PPT=2: two independent points per thread (ILP to hide trans latency)
//   * eigensolve C directly, shift to Cb in log2 domain (saves exp2 + 6 mul)
//   * t2 = -(t1+t3) from det(Cb)==1 (saves one v_log, also degenerate-safe)
//   * mu/alpha via rcp, hoisted once per thread, shared by both points
//   * float4 global->LDS staging (4.5 dwordx4 instead of 9 dword per thread)

#define BLOCK 256
#define PPT 2
#define PTS (BLOCK * PPT)          // 512 points per block
#define LDS_FLOATS (PTS * 9)       // 4608 floats = 18 KiB
#define LDS_VEC4 (LDS_FLOATS / 4)  // 1152 float4
#define LN2F 0.6931471805599453f

__device__ __forceinline__ float fast_acos(float x) {
    // Abramowitz-Stegun 4.4.45 style, |err| <= 6.8e-5 rad on [-1,1]
    const float ax = fabsf(x);
    const float t  = __builtin_amdgcn_sqrtf(1.0f - ax);
    const float p  = 1.5707288f + ax * (-0.2121144f + ax * (0.0742610f - ax * 0.0187293f));
    const float ac = t * p;
    return (x >= 0.0f) ? ac : (3.14159265358979f - ac);
}

__device__ __forceinline__ float ogden_point(
    const float* __restrict__ f,
    float h0, float h1, float h2,     // alpha_k / 2   (uniform)
    float ma0, float ma1, float ma2)  // mu_k / alpha_k (uniform)
{
    const float f00 = f[0], f01 = f[1], f02 = f[2];
    const float f10 = f[3], f11 = f[4], f12 = f[5];
    const float f20 = f[6], f21 = f[7], f22 = f[8];

    // ---- C = F^T F (symmetric) ----
    const float c00 = f00*f00 + f10*f10 + f20*f20;
    const float c01 = f00*f01 + f10*f11 + f20*f21;
    const float c02 = f00*f02 + f10*f12 + f20*f22;
    const float c11 = f01*f01 + f11*f11 + f21*f21;
    const float c12 = f01*f02 + f11*f12 + f21*f22;
    const float c22 = f02*f02 + f12*f12 + f22*f22;

    // ---- J = |det F| ----
    const float detF = f00*(f11*f22 - f12*f21)
                     - f01*(f10*f22 - f12*f20)
                     + f02*(f10*f21 - f11*f20);
    const float J     = fabsf(detF);
    const float log2J = __builtin_amdgcn_logf(J);   // log2(J)

    // ---- eigenvalues of C (trigonometric method); Cb handled in log domain ----
    const float q  = (c00 + c11 + c22) * (1.0f/3.0f);
    const float d0 = c00 - q, d1 = c11 - q, d2 = c22 - q;
    const float p2 = d0*d0 + d1*d1 + d2*d2
                   + 2.0f*(c01*c01 + c02*c02 + c12*c12);
    const float p    = __builtin_amdgcn_sqrtf(p2 * (1.0f/6.0f));
    const float invp = (p > 1e-20f) ? __builtin_amdgcn_rcpf(p) : 0.0f;

    const float m00 = d0*invp, m01 = c01*invp, m02 = c02*invp;
    const float m11 = d1*invp, m12 = c12*invp, m22 = d2*invp;
    const float detB = m00*(m11*m22 - m12*m12)
                     - m01*(m01*m22 - m12*m02)
                     + m02*(m01*m12 - m11*m02);
    float r = 0.5f * detB;
    r = fminf(1.0f, fmaxf(-1.0f, r));

    const float phi  = fast_acos(r) * (1.0f/3.0f);
    const float twop = 2.0f * p;
    float l1 = q + twop * __cosf(phi);
    float l3 = q + twop * __cosf(phi + 2.0943951023931953f); // + 2*pi/3

    l1 = fmaxf(l1, 1e-12f);
    l3 = fmaxf(l3, 1e-12f);

    // lamb_i(Cb) = J^(-2/3) * lamb_i(C)  ->  log2 shift by -(2/3) log2 J
    const float shift = -(2.0f/3.0f) * log2J;
    const float t1 = __builtin_amdgcn_logf(l1) + shift;
    const float t3 = __builtin_amdgcn_logf(l3) + shift;
    const float t2 = -(t1 + t3);            // det(Cb) == 1 exactly

    // ---- W_iso ----
    const float pw0 = __builtin_amdgcn_exp2f(h0*t1)
                    + __builtin_amdgcn_exp2f(h0*t2)
                    + __builtin_amdgcn_exp2f(h0*t3);
    const float pw1 = __builtin_amdgcn_exp2f(h1*t1)
                    + __builtin_amdgcn_exp2f(h1*t2)
                    + __builtin_amdgcn_exp2f(h1*t3);
    const float pw2 = __builtin_amdgcn_exp2f(h2*t1)
                    + __builtin_amdgcn_exp2f(h2*t2)
                    + __builtin_amdgcn_exp2f(h2*t3);
    float W = ma0*(pw0 - 3.0f) + ma1*(pw1 - 3.0f) + ma2*(pw2 - 3.0f);

    // ---- W_vol, KAPPA=100, BETA=2: 25*(J^2 - 2 lnJ - 1) ----
    W += 25.0f * (J*J - 2.0f*(log2J*LN2F) - 1.0f);
    return W;
}

__global__ __launch_bounds__(BLOCK) void ogden_kernel(
    const float* __restrict__ F,
    const float* __restrict__ mu,
    const float* __restrict__ alpha,
    float* __restrict__ out, int n)
{
    __shared__ float sF[LDS_FLOATS];

    const int tid  = threadIdx.x;
    const int base = blockIdx.x * PTS;

    // ---- coalesced float4 global -> LDS staging (linear order) ----
    int nf = (n - base) * 9;
    if (nf > LDS_FLOATS) nf = LDS_FLOATS;
    const int nf4 = nf >> 2;
    // base*9 floats = blockIdx*18432 bytes -> 16B-aligned
    const float4* __restrict__ G4 = (const float4*)(F + (long long)base * 9);
    float4* S4 = (float4*)sF;
    #pragma unroll
    for (int j = 0; j < LDS_VEC4 / BLOCK + 1; ++j) {   // 5 iters, last half-active
        const int idx = j * BLOCK + tid;
        if (idx < nf4) S4[idx] = G4[idx];
    }
    const int rem = nf & 3;    // scalar tail (only when (n-base)*9 % 4 != 0)
    if (tid < rem) sF[nf4 * 4 + tid] = F[(long long)base * 9 + nf4 * 4 + tid];
    __syncthreads();

    // ---- uniform per-k coefficients: computed once, shared by both points ----
    const float a0 = alpha[0], a1 = alpha[1], a2 = alpha[2];
    const float h0 = 0.5f * a0, h1 = 0.5f * a1, h2 = 0.5f * a2;
    const float ma0 = mu[0] * __builtin_amdgcn_rcpf(a0);
    const float ma1 = mu[1] * __builtin_amdgcn_rcpf(a1);
    const float ma2 = mu[2] * __builtin_amdgcn_rcpf(a2);

    // thread t handles points t and t+BLOCK: stride-9 LDS reads, gcd(9,32)=1
    // -> 2 lanes/bank in wave64 -> conflict-free. Two independent chains (ILP).
    const float W0 = ogden_point(&sF[tid * 9],           h0, h1, h2, ma0, ma1, ma2);
    const float W1 = ogden_point(&sF[(tid + BLOCK) * 9], h0, h1, h2, ma0, ma1, ma2);

    const int i0 = base + tid;
    if (i0 < n)         out[i0]         = W0;
    if (i0 + BLOCK < n) out[i0 + BLOCK] = W1;
}

extern "C" void kernel_launch(void* const* d_in, const int* in_sizes, int n_in,
                              void* d_out, int out_size, void* d_ws, size_t ws_size,
                              hipStream_t stream) {
    const float* F     = (const float*)d_in[0];
    const float* mu    = (const float*)d_in[1];
    const float* alpha = (const float*)d_in[2];
    float* out = (float*)d_out;
    const int n = out_size;

    const int grid = (n + PTS - 1) / PTS;
    ogden_kernel<<<grid, BLOCK, 0, stream>>>(F, mu, alpha, out, n);
}